// Round 4
// baseline (42.509 us; speedup 1.0000x reference)
//
#include <hip/hip_runtime.h>
#include <hip/hip_bf16.h>
#include <math.h>

// Problem constants: B=4, C=256, W=H=256, n=256
#define BDIM 4
#define CDIM 256
#define WH   65536
#define NIDX 256
#define NPOS 512          // 2*NIDX sorted gather positions
#define WSTR 8            // padded floats per (j,c) product record

__inline__ __device__ float wave_reduce_sum(float v) {
    #pragma unroll
    for (int off = 32; off > 0; off >>= 1)
        v += __shfl_down(v, off, 64);
    return v;
}

// ---------- kernel 0: sort 512 (idx,slot) keys ascending by idx ----------
// key = idx<<16 | slot;  slot j in [0,256) -> idx1[j], slot 256+j -> idx2[j]
__global__ __launch_bounds__(256) void sort_idx_kernel(
        const int* __restrict__ i1, const int* __restrict__ i2,
        unsigned int* __restrict__ sorted) {
    __shared__ unsigned int key[NPOS];
    const int t = threadIdx.x;
    key[t]       = ((unsigned int)i1[t] << 16) | (unsigned int)t;
    key[t + 256] = ((unsigned int)i2[t] << 16) | (unsigned int)(t + 256);
    __syncthreads();
    for (int k = 2; k <= NPOS; k <<= 1) {
        for (int jj = k >> 1; jj > 0; jj >>= 1) {
            #pragma unroll
            for (int i0 = 0; i0 < 2; ++i0) {
                const int i = t + (i0 << 8);
                const int l = i ^ jj;
                if (l > i) {
                    const unsigned int a = key[i], b = key[l];
                    const bool asc = ((i & k) == 0);
                    if ((a > b) == asc) { key[i] = b; key[l] = a; }
                }
            }
            __syncthreads();
        }
    }
    sorted[t] = key[t];
    sorted[t + 256] = key[t + 256];
}

// ---------- kernel 1: row-grouped gather + products, transposed write ----
// block = (b,c) row; lane t loads sorted positions t and t+256 from the
// block's OWN contiguous 256KB row -> monotonic addresses within each
// wave-load -> DRAM row-buffer hits instead of fresh activations.
__global__ __launch_bounds__(256) void gather_pass1(
        const float* __restrict__ x1, const float* __restrict__ x2,
        const unsigned int* __restrict__ sorted,
        float* __restrict__ prod) {
    const int blk = blockIdx.x;        // 0..1023
    const int b   = blk >> 8;
    const int c   = blk & 255;
    const int t   = threadIdx.x;

    __shared__ unsigned int skey[NPOS];
    __shared__ float v1[NPOS], v2[NPOS];
    skey[t]       = sorted[t];
    skey[t + 256] = sorted[t + 256];
    __syncthreads();

    const size_t base = ((size_t)(b * CDIM + c)) * (size_t)WH;

    const unsigned int k0 = skey[t];
    const unsigned int k1 = skey[t + 256];
    const unsigned int p0 = k0 >> 16, s0 = k0 & 0xFFFFu;
    const unsigned int p1 = k1 >> 16, s1 = k1 & 0xFFFFu;

    // 4 gather loads, monotonic within each wave-load instruction
    const float a0 = x1[base + p0];
    const float a1 = x1[base + p1];
    const float g0 = x2[base + p0];
    const float g1 = x2[base + p1];

    // unscramble to original slots via LDS
    v1[s0] = a0; v1[s1] = a1;
    v2[s0] = g0; v2[s1] = g1;
    __syncthreads();

    // thread t = position pair j: slots j (from idx1) and 256+j (from idx2)
    const float A1 = v1[t], B1 = v1[t + 256];
    const float A2 = v2[t], B2 = v2[t + 256];

    float* w = prod + (((((size_t)b << 8) | t) << 8) + c) * WSTR;
    float4 w0, w1;
    w0.x = A1 * B1; w0.y = A1 * A1; w0.z = B1 * B1; w0.w = A2 * B2;
    w1.x = A2 * A2; w1.y = B2 * B2; w1.z = 0.0f;    w1.w = 0.0f;
    *(float4*)(w)     = w0;
    *(float4*)(w + 4) = w1;
}

// ---------- kernel 2: per-(b,j) reduction over c (coalesced reads) -------
__global__ __launch_bounds__(256) void reduce_pass2(
        const float* __restrict__ prod, float* __restrict__ partial) {
    const int blk = blockIdx.x;       // (b,j): 0..1023
    const int b   = blk >> 8;
    const int j   = blk & 255;
    const int c   = threadIdx.x;

    const float4* p = (const float4*)(prod +
        (((((size_t)b << 8) | j) << 8) + c) * WSTR);
    const float4 u = p[0];
    const float4 v = p[1];

    float s[6] = { u.x, u.y, u.z, u.w, v.x, v.y };

    __shared__ float sm[4][6];
    const int lane = c & 63;
    const int wid  = c >> 6;
    #pragma unroll
    for (int k = 0; k < 6; ++k) {
        float r = wave_reduce_sum(s[k]);
        if (lane == 0) sm[wid][k] = r;
    }
    __syncthreads();

    if (c == 0) {
        float t[6];
        #pragma unroll
        for (int k = 0; k < 6; ++k)
            t[k] = sm[0][k] + sm[1][k] + sm[2][k] + sm[3][k];
        const float denom1 = fmaxf(sqrtf(t[1]) * sqrtf(t[2]), 1e-8f);
        const float denom2 = fmaxf(sqrtf(t[4]) * sqrtf(t[5]), 1e-8f);
        partial[blk] = fabsf(t[0] / denom1 - t[3] / denom2);
    }
}

// ---------- kernel 3: final mean over 1024 partials ----------------------
__global__ __launch_bounds__(256) void final_mean_kernel(
        const float* __restrict__ partial, float* __restrict__ out) {
    const int t = threadIdx.x;
    float v = partial[t] + partial[t + 256] + partial[t + 512] + partial[t + 768];
    v = wave_reduce_sum(v);
    __shared__ float sm[4];
    if ((t & 63) == 0) sm[t >> 6] = v;
    __syncthreads();
    if (t == 0)
        out[0] = (sm[0] + sm[1] + sm[2] + sm[3]) * (1.0f / (float)(BDIM * NIDX));
}

extern "C" void kernel_launch(void* const* d_in, const int* in_sizes, int n_in,
                              void* d_out, int out_size, void* d_ws, size_t ws_size,
                              hipStream_t stream) {
    const float* x1 = (const float*)d_in[0];
    const float* x2 = (const float*)d_in[1];
    const int*   i1 = (const int*)d_in[2];
    const int*   i2 = (const int*)d_in[3];
    float* out = (float*)d_out;

    unsigned int* sorted = (unsigned int*)d_ws;                  // 2 KB
    float* partial = (float*)((char*)d_ws + 4096);               // 4 KB
    float* prod    = (float*)((char*)d_ws + 8192);               // 8 MB

    sort_idx_kernel<<<1, 256, 0, stream>>>(i1, i2, sorted);
    gather_pass1<<<BDIM * CDIM, 256, 0, stream>>>(x1, x2, sorted, prod);
    reduce_pass2<<<BDIM * NIDX, 256, 0, stream>>>(prod, partial);
    final_mean_kernel<<<1, 256, 0, stream>>>(partial, out);
}

// Round 5
// 28.219 us; speedup vs baseline: 1.5064x; 1.5064x over previous
//
#include <hip/hip_runtime.h>
#include <hip/hip_bf16.h>
#include <math.h>

// Problem constants (from reference): B=4, C=256, W=H=256, n=256
#define BDIM 4
#define CDIM 256
#define WH   65536
#define NIDX 256

__inline__ __device__ float wave_reduce_sum(float v) {
    // full 64-lane butterfly
    #pragma unroll
    for (int off = 32; off > 0; off >>= 1)
        v += __shfl_down(v, off, 64);
    return v;
}

// One block per (b, j) pair. 256 threads, thread c handles channel c.
// Gather is memory-latency/line-throughput bound: ~1M unique scattered
// 4B loads -> ~986K distinct 64B lines (~63MB). Measured ~24us for the
// gather = 2.6-5.3 TB/s effective line fetch, i.e. at the random-access
// HBM bound. (R2 fused-atomic: +32us; R3 NT loads: +2us; R4 sorted
// wave-monotonic gather: +14us — all regressions.)
__global__ __launch_bounds__(256) void cossim_pairs_kernel(
        const float* __restrict__ x1, const float* __restrict__ x2,
        const int* __restrict__ i1, const int* __restrict__ i2,
        float* __restrict__ partial) {
    const int blk = blockIdx.x;       // 0 .. B*n-1
    const int b   = blk >> 8;         // / NIDX
    const int j   = blk & (NIDX - 1);
    const int c   = threadIdx.x;

    const int idx1 = i1[j];
    const int idx2 = i2[j];

    const size_t base = ((size_t)b * CDIM + c) * (size_t)WH;

    // 4 scattered loads per thread; issue all before use (ILP)
    const float a1 = x1[base + (size_t)idx1];
    const float b1 = x1[base + (size_t)idx2];
    const float a2 = x2[base + (size_t)idx1];
    const float b2 = x2[base + (size_t)idx2];

    float s[6];
    s[0] = a1 * b1;   // dot1
    s[1] = a1 * a1;   // |a1|^2
    s[2] = b1 * b1;   // |b1|^2
    s[3] = a2 * b2;   // dot2
    s[4] = a2 * a2;   // |a2|^2
    s[5] = b2 * b2;   // |b2|^2

    // wave-level reduce each of the 6 sums, then cross-wave via LDS
    __shared__ float sm[4][6];
    const int lane = c & 63;
    const int wid  = c >> 6;   // 0..3
    #pragma unroll
    for (int k = 0; k < 6; ++k) {
        float r = wave_reduce_sum(s[k]);
        if (lane == 0) sm[wid][k] = r;
    }
    __syncthreads();

    if (c == 0) {
        float t[6];
        #pragma unroll
        for (int k = 0; k < 6; ++k)
            t[k] = sm[0][k] + sm[1][k] + sm[2][k] + sm[3][k];
        const float denom1 = fmaxf(sqrtf(t[1]) * sqrtf(t[2]), 1e-8f);
        const float denom2 = fmaxf(sqrtf(t[4]) * sqrtf(t[5]), 1e-8f);
        const float D1 = t[0] / denom1;
        const float D2 = t[3] / denom2;
        partial[blk] = fabsf(D1 - D2);
    }
}

// Single-block final mean over B*n = 1024 partials.
__global__ __launch_bounds__(256) void final_mean_kernel(
        const float* __restrict__ partial, float* __restrict__ out) {
    const int t = threadIdx.x;  // 256 threads
    float v = partial[t] + partial[t + 256] + partial[t + 512] + partial[t + 768];
    v = wave_reduce_sum(v);
    __shared__ float sm[4];
    if ((t & 63) == 0) sm[t >> 6] = v;
    __syncthreads();
    if (t == 0)
        out[0] = (sm[0] + sm[1] + sm[2] + sm[3]) * (1.0f / (float)(BDIM * NIDX));
}

extern "C" void kernel_launch(void* const* d_in, const int* in_sizes, int n_in,
                              void* d_out, int out_size, void* d_ws, size_t ws_size,
                              hipStream_t stream) {
    const float* x1 = (const float*)d_in[0];
    const float* x2 = (const float*)d_in[1];
    const int*   i1 = (const int*)d_in[2];
    const int*   i2 = (const int*)d_in[3];
    float* out = (float*)d_out;
    float* partial = (float*)d_ws;   // needs B*n*4 = 4 KB

    const int nblocks = BDIM * NIDX;  // 1024
    cossim_pairs_kernel<<<nblocks, 256, 0, stream>>>(x1, x2, i1, i2, partial);
    final_mean_kernel<<<1, 256, 0, stream>>>(partial, out);
}